// Round 8
// baseline (229.034 us; speedup 1.0000x reference)
//
#include <hip/hip_runtime.h>

#define NN 50000      // nodes
#define EE 500000     // raw edges
#define ET 550000     // edges + self loops
#define EMB 128
#define HID 256
#define NH 8
#define RP 64
#define G1M_BLOCKS (NN / 16)                       // 3125 MFMA m-tiles
#define EDGE_BLOCKS ((ET + 255) / 256)             // 2149 edge blocks
#define NBUCK 196                                  // dst>>8 buckets
#define W1P_BLOCKS 16
#define W2P_BLOCKS 8
#define G2M_BLOCKS ((NN + 63) / 64)                // 782

typedef unsigned short u16;
typedef __attribute__((ext_vector_type(8))) short bf16x8;
typedef __attribute__((ext_vector_type(4))) float f32x4;

__device__ __forceinline__ float lrelu(float v) { return v > 0.f ? v : 0.2f * v; }
__device__ __forceinline__ float elu(float v) { return v > 0.f ? v : __expf(v) - 1.f; }
__device__ __forceinline__ u16 f2bf(float f) {
  unsigned int u = __float_as_uint(f);
  u += 0x7FFFu + ((u >> 16) & 1u);
  return (u16)(u >> 16);
}
__device__ __forceinline__ float bfl(unsigned int u) { return __uint_as_float(u << 16); }
__device__ __forceinline__ float bfh(unsigned int u) { return __uint_as_float(u & 0xFFFF0000u); }

// ---------- k_pre: W1 frag prep | W2 frag prep ----------------------------
__global__ __launch_bounds__(256) void k_pre(const float* __restrict__ W1,
    u16* __restrict__ Bbuf, const float* __restrict__ W2, u16* __restrict__ Bbuf2) {
  const int tid = threadIdx.x;
  const int b = blockIdx.x;
  const int l = tid & 63;
  const int quad = l >> 4, qr = l & 15;
  if (b < W1P_BLOCKS) {               // W1 -> bf16 B-frags (kt<4, nt<16)
    const int tile = b * 4 + (tid >> 6);
    const int kt = tile >> 4, nt = tile & 15;
    const float* src = W1 + (size_t)(kt * 32 + quad * 8) * HID + nt * 16 + qr;
    unsigned int p[4];
#pragma unroll
    for (int jp = 0; jp < 4; jp++) {
      u16 lo = f2bf(src[(2 * jp + 0) * HID]);
      u16 hi = f2bf(src[(2 * jp + 1) * HID]);
      p[jp] = (unsigned int)lo | ((unsigned int)hi << 16);
    }
    ((uint4*)Bbuf)[tile * 64 + l] = (uint4){p[0], p[1], p[2], p[3]};
    return;
  }
  // W2 -> bf16 B-frags (kt<8, nt<4)
  const int tile = (b - W1P_BLOCKS) * 4 + (tid >> 6);
  const int kt = tile >> 2, nt = tile & 3;
  const float* src = W2 + (size_t)(kt * 32 + quad * 8) * RP + nt * 16 + qr;
  unsigned int p[4];
#pragma unroll
  for (int jp = 0; jp < 4; jp++) {
    u16 lo = f2bf(src[(2 * jp + 0) * RP]);
    u16 hi = f2bf(src[(2 * jp + 1) * RP]);
    p[jp] = (unsigned int)lo | ((unsigned int)hi << 16);
  }
  ((uint4*)Bbuf2)[tile * 64 + l] = (uint4){p[0], p[1], p[2], p[3]};
}

// ---------- GEMM1 MFMA + fused per-block bucket histograms ----------------
__global__ __launch_bounds__(256) void k_g1hist(const float* __restrict__ x,
    const u16* __restrict__ Bbuf, const float* __restrict__ asw,
    const float* __restrict__ adw, u16* __restrict__ h1b,
    float* __restrict__ a_src, float* __restrict__ a_dst,
    const int* __restrict__ es, const int* __restrict__ ed,
    int* __restrict__ Gh) {
  const int tid = threadIdx.x;
  if (blockIdx.x >= G1M_BLOCKS) {
    // ---- edge bucket histogram (LDS atomics only) ----
    __shared__ int cnt[256];
    const int blk = blockIdx.x - G1M_BLOCKS;
    cnt[tid] = 0;
    __syncthreads();
    int i = blk * 256 + tid;
    if (i < ET) {
      int d = (i < EE) ? ed[i] : i - EE;
      atomicAdd(&cnt[d >> 8], 1);
    }
    __syncthreads();
    Gh[blk * 256 + tid] = cnt[tid];
    return;
  }
  const int w = tid >> 6, l = tid & 63;
  const int quad = l >> 4, qr = l & 15;
  const int node0 = blockIdx.x * 16;

  bf16x8 A[4];
  const float4* X4 = (const float4*)(x + (size_t)(node0 + qr) * EMB);
#pragma unroll
  for (int kt = 0; kt < 4; kt++) {
    float4 a0 = X4[kt * 8 + quad * 2];
    float4 a1 = X4[kt * 8 + quad * 2 + 1];
    A[kt][0] = (short)f2bf(a0.x); A[kt][1] = (short)f2bf(a0.y);
    A[kt][2] = (short)f2bf(a0.z); A[kt][3] = (short)f2bf(a0.w);
    A[kt][4] = (short)f2bf(a1.x); A[kt][5] = (short)f2bf(a1.y);
    A[kt][6] = (short)f2bf(a1.z); A[kt][7] = (short)f2bf(a1.w);
  }

  f32x4 acc[4];
  const bf16x8* Bf = (const bf16x8*)Bbuf;
#pragma unroll
  for (int nt = 0; nt < 4; nt++) {
    acc[nt] = (f32x4){0.f, 0.f, 0.f, 0.f};
    const int ntg = w * 4 + nt;
#pragma unroll
    for (int kt = 0; kt < 4; kt++) {
      bf16x8 B = Bf[(kt * 16 + ntg) * 64 + l];
      acc[nt] = __builtin_amdgcn_mfma_f32_16x16x32_bf16(A[kt], B, acc[nt], 0, 0, 0);
    }
  }

  float ps_s[4][2] = {};
  float ps_d[4][2] = {};
#pragma unroll
  for (int nt = 0; nt < 4; nt++) {
    const int colg = w * 64 + nt * 16 + qr;
    const float as = asw[colg], ad = adw[colg];
    const int hh = nt >> 1;
#pragma unroll
    for (int reg = 0; reg < 4; reg++) {
      float v = acc[nt][reg];
      int row = node0 + quad * 4 + reg;
      h1b[(size_t)row * HID + colg] = f2bf(v);
      ps_s[reg][hh] += v * as;
      ps_d[reg][hh] += v * ad;
    }
  }
#pragma unroll
  for (int reg = 0; reg < 4; reg++) {
#pragma unroll
    for (int hh = 0; hh < 2; hh++) {
      float vs = ps_s[reg][hh], vd = ps_d[reg][hh];
      vs += __shfl_xor(vs, 8, 64); vs += __shfl_xor(vs, 4, 64);
      vs += __shfl_xor(vs, 2, 64); vs += __shfl_xor(vs, 1, 64);
      vd += __shfl_xor(vd, 8, 64); vd += __shfl_xor(vd, 4, 64);
      vd += __shfl_xor(vd, 2, 64); vd += __shfl_xor(vd, 1, 64);
      if (qr == 0) {
        int row = node0 + quad * 4 + reg;
        int head = 2 * w + hh;
        a_src[row * NH + head] = vs;
        a_dst[row * NH + head] = vd;
      }
    }
  }
}

// ---------- k_bscan: per-bucket column scan of Gh -> offsets + totals -----
// block b: Gh[k][b] <- sum_{k'<k} Gh[k'][b]; btot[b] = bucket size
__global__ __launch_bounds__(256) void k_bscan(int* __restrict__ Gh,
                                               int* __restrict__ btot) {
  __shared__ int s[256];
  const int t = threadIdx.x;
  const int b = blockIdx.x;
  int off = 0;
  for (int k0 = 0; k0 < EDGE_BLOCKS; k0 += 256) {
    int k = k0 + t;
    int v = (k < EDGE_BLOCKS) ? Gh[k * 256 + b] : 0;
    s[t] = v;
    __syncthreads();
    for (int o = 1; o < 256; o <<= 1) {
      int y = (t >= o) ? s[t - o] : 0;
      __syncthreads();
      s[t] += y;
      __syncthreads();
    }
    if (k < EDGE_BLOCKS) Gh[k * 256 + b] = off + s[t] - v;
    int tot = s[255];
    __syncthreads();
    off += tot;
  }
  if (t == 0) btot[b] = off;
}

// ---------- k_bstart: scan bucket totals ----------------------------------
__global__ __launch_bounds__(256) void k_bstart(const int* __restrict__ btot,
                                                int* __restrict__ bstart) {
  __shared__ int s[256];
  const int t = threadIdx.x;
  const int v = (t < NBUCK) ? btot[t] : 0;
  s[t] = v;
  __syncthreads();
  for (int o = 1; o < 256; o <<= 1) {
    int y = (t >= o) ? s[t - o] : 0;
    __syncthreads();
    s[t] += y;
    __syncthreads();
  }
  if (t < NBUCK) bstart[t] = s[t] - v;
  if (t == 0) bstart[NBUCK] = ET;
}

// ---------- k_bscatter: atomic-free edge scatter into bucket order --------
__global__ __launch_bounds__(256) void k_bscatter(const int* __restrict__ es,
    const int* __restrict__ ed, const int* __restrict__ Gh,
    const int* __restrict__ bstart, int* __restrict__ ebuf) {
  __shared__ int cnt[256];
  const int tid = threadIdx.x;
  const int blk = blockIdx.x;
  cnt[tid] = 0;
  __syncthreads();
  int i = blk * 256 + tid;
  if (i < ET) {
    int s, d;
    if (i < EE) { s = es[i]; d = ed[i]; } else { s = d = i - EE; }
    int bkt = d >> 8;
    int r = atomicAdd(&cnt[bkt], 1);
    int pos = bstart[bkt] + Gh[blk * 256 + bkt] + r;
    ebuf[pos] = ((d & 255) << 16) | s;
  }
}

// ---------- k_csr: per-bucket CSR finalize (LDS only) ---------------------
// block b owns nodes [b*256, b*256+256); emits rowp + col for its segment
__global__ __launch_bounds__(256) void k_csr(const int* __restrict__ ebuf,
    const int* __restrict__ bstart, int* __restrict__ rowp, int* __restrict__ col) {
  __shared__ int cnt[256];
  __shared__ int cur[256];
  const int t = threadIdx.x;
  const int b = blockIdx.x;
  const int segs = bstart[b], sege = bstart[b + 1];
  cnt[t] = 0;
  __syncthreads();
  for (int i = segs + t; i < sege; i += 256)
    atomicAdd(&cnt[(ebuf[i] >> 16) & 255], 1);
  __syncthreads();
  // exclusive scan of cnt
  int v = cnt[t];
  cur[t] = v;
  __syncthreads();
  for (int o = 1; o < 256; o <<= 1) {
    int y = (t >= o) ? cur[t - o] : 0;
    __syncthreads();
    cur[t] += y;
    __syncthreads();
  }
  int base = segs + cur[t] - v;
  int node = b * 256 + t;
  if (node <= NN) rowp[node] = base;
  cur[t] = base;
  __syncthreads();
  for (int i = segs + t; i < sege; i += 256) {
    int p = ebuf[i];
    int pos = atomicAdd(&cur[(p >> 16) & 255], 1);
    col[pos] = p & 0xFFFF;
  }
}

// ---------- Layer-1 aggregation: half-wave edge-parallel, bf16 x2 out -----
__global__ __launch_bounds__(256) void k_agg1(const int* __restrict__ rowp,
    const int* __restrict__ col, const float* __restrict__ a_src,
    const float* __restrict__ a_dst, const u16* __restrict__ h1b,
    const float* __restrict__ b1, u16* __restrict__ x2b) {
  int node = (blockIdx.x * 256 + threadIdx.x) >> 6;
  if (node >= NN) return;
  const int lane = threadIdx.x & 63;
  const int half = lane >> 5;
  const int hl = lane & 31;     // owns cols 8*hl .. 8*hl+7
  const int h = hl >> 2;        // head
  const float ad = a_dst[node * NH + h];
  float num[8] = {};
  float den = 0.f;
  const int beg = rowp[node], end = rowp[node + 1];
  int e = beg + half;
  int sn = (e < end) ? col[e] : 0;
  for (; e < end; e += 2) {
    int s = sn;
    if (e + 2 < end) sn = col[e + 2];
    float w = __expf(lrelu(a_src[s * NH + h] + ad));
    uint4 hv = ((const uint4*)(h1b + (size_t)s * HID))[hl];
    den += w;
    num[0] += w * bfl(hv.x); num[1] += w * bfh(hv.x);
    num[2] += w * bfl(hv.y); num[3] += w * bfh(hv.y);
    num[4] += w * bfl(hv.z); num[5] += w * bfh(hv.z);
    num[6] += w * bfl(hv.w); num[7] += w * bfh(hv.w);
  }
  den += __shfl_xor(den, 32, 64);
#pragma unroll
  for (int j = 0; j < 8; j++) num[j] += __shfl_xor(num[j], 32, 64);
  if (half == 0) {
    const float inv = 1.f / (den + 1e-16f);
    const float4 b0 = ((const float4*)(b1 + hl * 8))[0];
    const float4 b1v = ((const float4*)(b1 + hl * 8))[1];
    float o[8];
    o[0] = elu(num[0] * inv + b0.x);
    o[1] = elu(num[1] * inv + b0.y);
    o[2] = elu(num[2] * inv + b0.z);
    o[3] = elu(num[3] * inv + b0.w);
    o[4] = elu(num[4] * inv + b1v.x);
    o[5] = elu(num[5] * inv + b1v.y);
    o[6] = elu(num[6] * inv + b1v.z);
    o[7] = elu(num[7] * inv + b1v.w);
    unsigned int dw[4];
#pragma unroll
    for (int jp = 0; jp < 4; jp++)
      dw[jp] = (unsigned int)f2bf(o[2 * jp]) | ((unsigned int)f2bf(o[2 * jp + 1]) << 16);
    ((uint4*)(x2b + (size_t)node * HID))[hl] = (uint4){dw[0], dw[1], dw[2], dw[3]};
  }
}

// ---------- GEMM 2 via MFMA: h2 = x2b @ W2 (bf16 out) + att dots ----------
__global__ __launch_bounds__(256) void k_gemm2m(const u16* __restrict__ x2b,
    const u16* __restrict__ Bbuf2, const float* __restrict__ asw,
    const float* __restrict__ adw, u16* __restrict__ h2b,
    float* __restrict__ a_src2, float* __restrict__ a_dst2) {
  const int tid = threadIdx.x;
  const int w = tid >> 6, l = tid & 63;
  const int quad = l >> 4, qr = l & 15;
  const int row0 = blockIdx.x * 64 + w * 16;
  const int rowA = row0 + qr;
  const int rowA_ld = rowA < NN ? rowA : NN - 1;

  bf16x8 A[8];
  const bf16x8* Xa = (const bf16x8*)(x2b + (size_t)rowA_ld * HID);
#pragma unroll
  for (int kt = 0; kt < 8; kt++) A[kt] = Xa[kt * 4 + quad];

  f32x4 acc[4];
  const bf16x8* Bf = (const bf16x8*)Bbuf2;
#pragma unroll
  for (int nt = 0; nt < 4; nt++) {
    acc[nt] = (f32x4){0.f, 0.f, 0.f, 0.f};
#pragma unroll
    for (int kt = 0; kt < 8; kt++) {
      bf16x8 B = Bf[(kt * 4 + nt) * 64 + l];
      acc[nt] = __builtin_amdgcn_mfma_f32_16x16x32_bf16(A[kt], B, acc[nt], 0, 0, 0);
    }
  }

  float ps_s[4] = {}, ps_d[4] = {};
#pragma unroll
  for (int nt = 0; nt < 4; nt++) {
    const int colg = nt * 16 + qr;
    const float as = asw[colg], ad = adw[colg];
#pragma unroll
    for (int reg = 0; reg < 4; reg++) {
      float v = acc[nt][reg];
      int row = row0 + quad * 4 + reg;
      if (row < NN) h2b[(size_t)row * RP + colg] = f2bf(v);
      ps_s[reg] += v * as;
      ps_d[reg] += v * ad;
    }
  }
#pragma unroll
  for (int reg = 0; reg < 4; reg++) {
    float vs = ps_s[reg], vd = ps_d[reg];
    vs += __shfl_xor(vs, 8, 64); vs += __shfl_xor(vs, 4, 64);
    vs += __shfl_xor(vs, 2, 64); vs += __shfl_xor(vs, 1, 64);
    vd += __shfl_xor(vd, 8, 64); vd += __shfl_xor(vd, 4, 64);
    vd += __shfl_xor(vd, 2, 64); vd += __shfl_xor(vd, 1, 64);
    int row = row0 + quad * 4 + reg;
    if (qr == 0 && row < NN) { a_src2[row] = vs; a_dst2[row] = vd; }
  }
}

// ---------- Layer-2 aggregation: quarter-wave edge-parallel ---------------
__global__ __launch_bounds__(256) void k_agg2(const int* __restrict__ rowp,
    const int* __restrict__ col, const float* __restrict__ a_src2,
    const float* __restrict__ a_dst2, const u16* __restrict__ h2b,
    const float* __restrict__ b2, float* __restrict__ out) {
  int node = (blockIdx.x * 256 + threadIdx.x) >> 6;
  if (node >= NN) return;
  const int lane = threadIdx.x & 63;
  const int q = lane >> 4;
  const int ql = lane & 15;     // owns cols 4*ql .. 4*ql+3
  const float ad = a_dst2[node];
  float num[4] = {};
  float den = 0.f;
  const int beg = rowp[node], end = rowp[node + 1];
  int e = beg + q;
  int sn = (e < end) ? col[e] : 0;
  for (; e < end; e += 4) {
    int s = sn;
    if (e + 4 < end) sn = col[e + 4];
    float w = __expf(lrelu(a_src2[s] + ad));
    uint2 hv = ((const uint2*)(h2b + (size_t)s * RP))[ql];
    den += w;
    num[0] += w * bfl(hv.x); num[1] += w * bfh(hv.x);
    num[2] += w * bfl(hv.y); num[3] += w * bfh(hv.y);
  }
  den += __shfl_xor(den, 16, 64);
  den += __shfl_xor(den, 32, 64);
#pragma unroll
  for (int j = 0; j < 4; j++) {
    num[j] += __shfl_xor(num[j], 16, 64);
    num[j] += __shfl_xor(num[j], 32, 64);
  }
  if (q == 0) {
    const float inv = 1.f / (den + 1e-16f);
    const float4 b = ((const float4*)(b2 + ql * 4))[0];
    float4 o;
    o.x = num[0] * inv + b.x;
    o.y = num[1] * inv + b.y;
    o.z = num[2] * inv + b.z;
    o.w = num[3] * inv + b.w;
    ((float4*)(out + (size_t)node * RP + ql * 4))[0] = o;
  }
}

extern "C" void kernel_launch(void* const* d_in, const int* in_sizes, int n_in,
                              void* d_out, int out_size, void* d_ws, size_t ws_size,
                              hipStream_t stream) {
  const float* x   = (const float*)d_in[0];
  const float* W1  = (const float*)d_in[1];
  const float* a1s = (const float*)d_in[2];
  const float* a1d = (const float*)d_in[3];
  const float* b1  = (const float*)d_in[4];
  const float* W2  = (const float*)d_in[5];
  const float* a2s = (const float*)d_in[6];
  const float* a2d = (const float*)d_in[7];
  const float* b2  = (const float*)d_in[8];
  const int*   es  = (const int*)d_in[9];
  const int*   ed  = es + EE;
  float* out = (float*)d_out;

  // workspace layout
  u16*   h1b    = (u16*)d_ws;                        // N*256 bf16 (reused as h2b)
  u16*   x2b    = h1b + (size_t)NN * HID;            // N*256 bf16
  float* asrc1  = (float*)(x2b + (size_t)NN * HID);  // N*8
  float* adst1  = asrc1 + (size_t)NN * NH;           // N*8
  int*   rowp   = (int*)(adst1 + (size_t)NN * NH);   // N+1
  int*   col    = rowp + NN + 1;                     // ET
  int*   Gh     = col + ET;                          // EDGE_BLOCKS*256
  int*   ebuf   = Gh + EDGE_BLOCKS * 256;            // ET packed edges
  int*   btot   = ebuf + ET;                         // 256
  int*   bstart = btot + 256;                        // 256
  u16*   Bbuf   = (u16*)(bstart + 256);              // 128*256 bf16 frag-major
  u16*   Bbuf2  = Bbuf + (size_t)EMB * HID;          // 256*64 bf16 frag-major
  u16*   h2b    = h1b;
  float* asrc2  = asrc1;
  float* adst2  = adst1;

  // W prep
  k_pre<<<W1P_BLOCKS + W2P_BLOCKS, 256, 0, stream>>>(W1, Bbuf, W2, Bbuf2);

  // MFMA GEMM1 fused with bucket histogram (LDS atomics only)
  k_g1hist<<<G1M_BLOCKS + EDGE_BLOCKS, 256, 0, stream>>>(
      x, Bbuf, a1s, a1d, h1b, asrc1, adst1, es, ed, Gh);

  // atomic-free CSR build
  k_bscan<<<NBUCK, 256, 0, stream>>>(Gh, btot);
  k_bstart<<<1, 256, 0, stream>>>(btot, bstart);
  k_bscatter<<<EDGE_BLOCKS, 256, 0, stream>>>(es, ed, Gh, bstart, ebuf);
  k_csr<<<NBUCK, 256, 0, stream>>>(ebuf, bstart, rowp, col);

  k_agg1<<<(NN * 64 + 255) / 256, 256, 0, stream>>>(rowp, col, asrc1, adst1, h1b, b1, x2b);
  k_gemm2m<<<G2M_BLOCKS, 256, 0, stream>>>(x2b, Bbuf2, a2s, a2d, h2b, asrc2, adst2);
  k_agg2<<<(NN * 64 + 255) / 256, 256, 0, stream>>>(rowp, col, asrc2, adst2, h2b, b2, out);
}

// Round 9
// 224.398 us; speedup vs baseline: 1.0207x; 1.0207x over previous
//
#include <hip/hip_runtime.h>

#define NN 50000      // nodes
#define EE 500000     // raw edges
#define ET 550000     // edges + self loops
#define EMB 128
#define HID 256
#define NH 8
#define RP 64
#define G1M_BLOCKS (NN / 16)                       // 3125 MFMA m-tiles
#define EDGE_BLOCKS ((ET + 255) / 256)             // 2149 edge blocks
#define NBUCK 196                                  // dst>>8 buckets
#define W1P_BLOCKS 16
#define W2P_BLOCKS 8
#define G2M_BLOCKS ((NN + 63) / 64)                // 782

typedef unsigned short u16;
typedef __attribute__((ext_vector_type(8))) short bf16x8;
typedef __attribute__((ext_vector_type(4))) float f32x4;

__device__ __forceinline__ float lrelu(float v) { return v > 0.f ? v : 0.2f * v; }
__device__ __forceinline__ float elu(float v) { return v > 0.f ? v : __expf(v) - 1.f; }
__device__ __forceinline__ u16 f2bf(float f) {
  unsigned int u = __float_as_uint(f);
  u += 0x7FFFu + ((u >> 16) & 1u);
  return (u16)(u >> 16);
}
__device__ __forceinline__ float bfl(unsigned int u) { return __uint_as_float(u << 16); }
__device__ __forceinline__ float bfh(unsigned int u) { return __uint_as_float(u & 0xFFFF0000u); }

// ---------- k_pre: W1 prep | W2 prep | edge bucket histograms -------------
__global__ __launch_bounds__(256) void k_pre(const float* __restrict__ W1,
    u16* __restrict__ Bbuf, const float* __restrict__ W2, u16* __restrict__ Bbuf2,
    const int* __restrict__ ed, int* __restrict__ Gh) {
  const int tid = threadIdx.x;
  const int b = blockIdx.x;
  if (b >= W1P_BLOCKS + W2P_BLOCKS) {
    // ---- per-block edge bucket histogram (LDS atomics only) ----
    __shared__ int cnt[256];
    const int blk = b - W1P_BLOCKS - W2P_BLOCKS;
    cnt[tid] = 0;
    __syncthreads();
    int i = blk * 256 + tid;
    if (i < ET) {
      int d = (i < EE) ? ed[i] : i - EE;
      atomicAdd(&cnt[d >> 8], 1);
    }
    __syncthreads();
    Gh[blk * 256 + tid] = cnt[tid];
    return;
  }
  const int l = tid & 63;
  const int quad = l >> 4, qr = l & 15;
  if (b < W1P_BLOCKS) {               // W1 -> bf16 B-frags (kt<4, nt<16)
    const int tile = b * 4 + (tid >> 6);
    const int kt = tile >> 4, nt = tile & 15;
    const float* src = W1 + (size_t)(kt * 32 + quad * 8) * HID + nt * 16 + qr;
    unsigned int p[4];
#pragma unroll
    for (int jp = 0; jp < 4; jp++) {
      u16 lo = f2bf(src[(2 * jp + 0) * HID]);
      u16 hi = f2bf(src[(2 * jp + 1) * HID]);
      p[jp] = (unsigned int)lo | ((unsigned int)hi << 16);
    }
    ((uint4*)Bbuf)[tile * 64 + l] = (uint4){p[0], p[1], p[2], p[3]};
    return;
  }
  // W2 -> bf16 B-frags (kt<8, nt<4)
  const int tile = (b - W1P_BLOCKS) * 4 + (tid >> 6);
  const int kt = tile >> 2, nt = tile & 3;
  const float* src = W2 + (size_t)(kt * 32 + quad * 8) * RP + nt * 16 + qr;
  unsigned int p[4];
#pragma unroll
  for (int jp = 0; jp < 4; jp++) {
    u16 lo = f2bf(src[(2 * jp + 0) * RP]);
    u16 hi = f2bf(src[(2 * jp + 1) * RP]);
    p[jp] = (unsigned int)lo | ((unsigned int)hi << 16);
  }
  ((uint4*)Bbuf2)[tile * 64 + l] = (uint4){p[0], p[1], p[2], p[3]};
}

// ---------- GEMM1 MFMA + fused per-bucket column scan of Gh ---------------
__global__ __launch_bounds__(256) void k_g1(const float* __restrict__ x,
    const u16* __restrict__ Bbuf, const float* __restrict__ asw,
    const float* __restrict__ adw, u16* __restrict__ h1b,
    float* __restrict__ a_src, float* __restrict__ a_dst,
    int* __restrict__ Gh, int* __restrict__ btot) {
  const int tid = threadIdx.x;
  if (blockIdx.x >= G1M_BLOCKS) {
    // ---- bscan body: column scan of Gh for bucket b ----
    __shared__ int s[256];
    const int t = tid;
    const int b = blockIdx.x - G1M_BLOCKS;
    int off = 0;
    for (int k0 = 0; k0 < EDGE_BLOCKS; k0 += 256) {
      int k = k0 + t;
      int v = (k < EDGE_BLOCKS) ? Gh[k * 256 + b] : 0;
      s[t] = v;
      __syncthreads();
      for (int o = 1; o < 256; o <<= 1) {
        int y = (t >= o) ? s[t - o] : 0;
        __syncthreads();
        s[t] += y;
        __syncthreads();
      }
      if (k < EDGE_BLOCKS) Gh[k * 256 + b] = off + s[t] - v;
      int tot = s[255];
      __syncthreads();
      off += tot;
    }
    if (t == 0) btot[b] = off;
    return;
  }
  const int w = tid >> 6, l = tid & 63;
  const int quad = l >> 4, qr = l & 15;
  const int node0 = blockIdx.x * 16;

  bf16x8 A[4];
  const float4* X4 = (const float4*)(x + (size_t)(node0 + qr) * EMB);
#pragma unroll
  for (int kt = 0; kt < 4; kt++) {
    float4 a0 = X4[kt * 8 + quad * 2];
    float4 a1 = X4[kt * 8 + quad * 2 + 1];
    A[kt][0] = (short)f2bf(a0.x); A[kt][1] = (short)f2bf(a0.y);
    A[kt][2] = (short)f2bf(a0.z); A[kt][3] = (short)f2bf(a0.w);
    A[kt][4] = (short)f2bf(a1.x); A[kt][5] = (short)f2bf(a1.y);
    A[kt][6] = (short)f2bf(a1.z); A[kt][7] = (short)f2bf(a1.w);
  }

  f32x4 acc[4];
  const bf16x8* Bf = (const bf16x8*)Bbuf;
#pragma unroll
  for (int nt = 0; nt < 4; nt++) {
    acc[nt] = (f32x4){0.f, 0.f, 0.f, 0.f};
    const int ntg = w * 4 + nt;
#pragma unroll
    for (int kt = 0; kt < 4; kt++) {
      bf16x8 B = Bf[(kt * 16 + ntg) * 64 + l];
      acc[nt] = __builtin_amdgcn_mfma_f32_16x16x32_bf16(A[kt], B, acc[nt], 0, 0, 0);
    }
  }

  float ps_s[4][2] = {};
  float ps_d[4][2] = {};
#pragma unroll
  for (int nt = 0; nt < 4; nt++) {
    const int colg = w * 64 + nt * 16 + qr;
    const float as = asw[colg], ad = adw[colg];
    const int hh = nt >> 1;
#pragma unroll
    for (int reg = 0; reg < 4; reg++) {
      float v = acc[nt][reg];
      int row = node0 + quad * 4 + reg;
      h1b[(size_t)row * HID + colg] = f2bf(v);
      ps_s[reg][hh] += v * as;
      ps_d[reg][hh] += v * ad;
    }
  }
#pragma unroll
  for (int reg = 0; reg < 4; reg++) {
#pragma unroll
    for (int hh = 0; hh < 2; hh++) {
      float vs = ps_s[reg][hh], vd = ps_d[reg][hh];
      vs += __shfl_xor(vs, 8, 64); vs += __shfl_xor(vs, 4, 64);
      vs += __shfl_xor(vs, 2, 64); vs += __shfl_xor(vs, 1, 64);
      vd += __shfl_xor(vd, 8, 64); vd += __shfl_xor(vd, 4, 64);
      vd += __shfl_xor(vd, 2, 64); vd += __shfl_xor(vd, 1, 64);
      if (qr == 0) {
        int row = node0 + quad * 4 + reg;
        int head = 2 * w + hh;
        a_src[row * NH + head] = vs;
        a_dst[row * NH + head] = vd;
      }
    }
  }
}

// ---------- k_bstart: scan bucket totals ----------------------------------
__global__ __launch_bounds__(256) void k_bstart(const int* __restrict__ btot,
                                                int* __restrict__ bstart) {
  __shared__ int s[256];
  const int t = threadIdx.x;
  const int v = (t < NBUCK) ? btot[t] : 0;
  s[t] = v;
  __syncthreads();
  for (int o = 1; o < 256; o <<= 1) {
    int y = (t >= o) ? s[t - o] : 0;
    __syncthreads();
    s[t] += y;
    __syncthreads();
  }
  if (t < NBUCK) bstart[t] = s[t] - v;
  if (t == 0) bstart[NBUCK] = ET;
}

// ---------- k_bscatter: atomic-free edge scatter into bucket order --------
__global__ __launch_bounds__(256) void k_bscatter(const int* __restrict__ es,
    const int* __restrict__ ed, const int* __restrict__ Gh,
    const int* __restrict__ bstart, int* __restrict__ ebuf) {
  __shared__ int cnt[256];
  const int tid = threadIdx.x;
  const int blk = blockIdx.x;
  cnt[tid] = 0;
  __syncthreads();
  int i = blk * 256 + tid;
  if (i < ET) {
    int s, d;
    if (i < EE) { s = es[i]; d = ed[i]; } else { s = d = i - EE; }
    int bkt = d >> 8;
    int r = atomicAdd(&cnt[bkt], 1);
    int pos = bstart[bkt] + Gh[blk * 256 + bkt] + r;
    ebuf[pos] = ((d & 255) << 16) | s;
  }
}

// ---------- k_csr: per-bucket CSR finalize (LDS only) ---------------------
__global__ __launch_bounds__(256) void k_csr(const int* __restrict__ ebuf,
    const int* __restrict__ bstart, int* __restrict__ rowp, int* __restrict__ col) {
  __shared__ int cnt[256];
  __shared__ int cur[256];
  const int t = threadIdx.x;
  const int b = blockIdx.x;
  const int segs = bstart[b], sege = bstart[b + 1];
  cnt[t] = 0;
  __syncthreads();
  for (int i = segs + t; i < sege; i += 256)
    atomicAdd(&cnt[(ebuf[i] >> 16) & 255], 1);
  __syncthreads();
  int v = cnt[t];
  cur[t] = v;
  __syncthreads();
  for (int o = 1; o < 256; o <<= 1) {
    int y = (t >= o) ? cur[t - o] : 0;
    __syncthreads();
    cur[t] += y;
    __syncthreads();
  }
  int base = segs + cur[t] - v;
  int node = b * 256 + t;
  if (node <= NN) rowp[node] = base;
  cur[t] = base;
  __syncthreads();
  for (int i = segs + t; i < sege; i += 256) {
    int p = ebuf[i];
    int pos = atomicAdd(&cur[(p >> 16) & 255], 1);
    col[pos] = p & 0xFFFF;
  }
}

// ---------- Layer-1 aggregation: half-wave, 2 edges/half in flight --------
__global__ __launch_bounds__(256) void k_agg1(const int* __restrict__ rowp,
    const int* __restrict__ col, const float* __restrict__ a_src,
    const float* __restrict__ a_dst, const u16* __restrict__ h1b,
    const float* __restrict__ b1, u16* __restrict__ x2b) {
  int node = (blockIdx.x * 256 + threadIdx.x) >> 6;
  if (node >= NN) return;
  const int lane = threadIdx.x & 63;
  const int half = lane >> 5;
  const int hl = lane & 31;     // owns cols 8*hl .. 8*hl+7
  const int h = hl >> 2;        // head
  const float ad = a_dst[node * NH + h];
  float num[8] = {};
  float den = 0.f;
  const int beg = rowp[node], end = rowp[node + 1];
  int e = beg + half;
  int s0 = (e < end) ? col[e] : 0;
  int s1 = (e + 2 < end) ? col[e + 2] : 0;
  while (e + 2 < end) {
    const int cs0 = s0, cs1 = s1;
    if (e + 4 < end) s0 = col[e + 4];
    if (e + 6 < end) s1 = col[e + 6];
    float w0 = __expf(lrelu(a_src[cs0 * NH + h] + ad));
    float w1 = __expf(lrelu(a_src[cs1 * NH + h] + ad));
    uint4 hv0 = ((const uint4*)(h1b + (size_t)cs0 * HID))[hl];
    uint4 hv1 = ((const uint4*)(h1b + (size_t)cs1 * HID))[hl];
    den += w0 + w1;
    num[0] += w0 * bfl(hv0.x) + w1 * bfl(hv1.x);
    num[1] += w0 * bfh(hv0.x) + w1 * bfh(hv1.x);
    num[2] += w0 * bfl(hv0.y) + w1 * bfl(hv1.y);
    num[3] += w0 * bfh(hv0.y) + w1 * bfh(hv1.y);
    num[4] += w0 * bfl(hv0.z) + w1 * bfl(hv1.z);
    num[5] += w0 * bfh(hv0.z) + w1 * bfh(hv1.z);
    num[6] += w0 * bfl(hv0.w) + w1 * bfl(hv1.w);
    num[7] += w0 * bfh(hv0.w) + w1 * bfh(hv1.w);
    e += 4;
  }
  if (e < end) {
    float w0 = __expf(lrelu(a_src[s0 * NH + h] + ad));
    uint4 hv0 = ((const uint4*)(h1b + (size_t)s0 * HID))[hl];
    den += w0;
    num[0] += w0 * bfl(hv0.x); num[1] += w0 * bfh(hv0.x);
    num[2] += w0 * bfl(hv0.y); num[3] += w0 * bfh(hv0.y);
    num[4] += w0 * bfl(hv0.z); num[5] += w0 * bfh(hv0.z);
    num[6] += w0 * bfl(hv0.w); num[7] += w0 * bfh(hv0.w);
  }
  den += __shfl_xor(den, 32, 64);
#pragma unroll
  for (int j = 0; j < 8; j++) num[j] += __shfl_xor(num[j], 32, 64);
  if (half == 0) {
    const float inv = 1.f / (den + 1e-16f);
    const float4 b0 = ((const float4*)(b1 + hl * 8))[0];
    const float4 b1v = ((const float4*)(b1 + hl * 8))[1];
    float o[8];
    o[0] = elu(num[0] * inv + b0.x);
    o[1] = elu(num[1] * inv + b0.y);
    o[2] = elu(num[2] * inv + b0.z);
    o[3] = elu(num[3] * inv + b0.w);
    o[4] = elu(num[4] * inv + b1v.x);
    o[5] = elu(num[5] * inv + b1v.y);
    o[6] = elu(num[6] * inv + b1v.z);
    o[7] = elu(num[7] * inv + b1v.w);
    unsigned int dw[4];
#pragma unroll
    for (int jp = 0; jp < 4; jp++)
      dw[jp] = (unsigned int)f2bf(o[2 * jp]) | ((unsigned int)f2bf(o[2 * jp + 1]) << 16);
    ((uint4*)(x2b + (size_t)node * HID))[hl] = (uint4){dw[0], dw[1], dw[2], dw[3]};
  }
}

// ---------- GEMM 2 via MFMA: h2 = x2b @ W2 (bf16 out) + att dots ----------
__global__ __launch_bounds__(256) void k_gemm2m(const u16* __restrict__ x2b,
    const u16* __restrict__ Bbuf2, const float* __restrict__ asw,
    const float* __restrict__ adw, u16* __restrict__ h2b,
    float* __restrict__ a_src2, float* __restrict__ a_dst2) {
  const int tid = threadIdx.x;
  const int w = tid >> 6, l = tid & 63;
  const int quad = l >> 4, qr = l & 15;
  const int row0 = blockIdx.x * 64 + w * 16;
  const int rowA = row0 + qr;
  const int rowA_ld = rowA < NN ? rowA : NN - 1;

  bf16x8 A[8];
  const bf16x8* Xa = (const bf16x8*)(x2b + (size_t)rowA_ld * HID);
#pragma unroll
  for (int kt = 0; kt < 8; kt++) A[kt] = Xa[kt * 4 + quad];

  f32x4 acc[4];
  const bf16x8* Bf = (const bf16x8*)Bbuf2;
#pragma unroll
  for (int nt = 0; nt < 4; nt++) {
    acc[nt] = (f32x4){0.f, 0.f, 0.f, 0.f};
#pragma unroll
    for (int kt = 0; kt < 8; kt++) {
      bf16x8 B = Bf[(kt * 4 + nt) * 64 + l];
      acc[nt] = __builtin_amdgcn_mfma_f32_16x16x32_bf16(A[kt], B, acc[nt], 0, 0, 0);
    }
  }

  float ps_s[4] = {}, ps_d[4] = {};
#pragma unroll
  for (int nt = 0; nt < 4; nt++) {
    const int colg = nt * 16 + qr;
    const float as = asw[colg], ad = adw[colg];
#pragma unroll
    for (int reg = 0; reg < 4; reg++) {
      float v = acc[nt][reg];
      int row = row0 + quad * 4 + reg;
      if (row < NN) h2b[(size_t)row * RP + colg] = f2bf(v);
      ps_s[reg] += v * as;
      ps_d[reg] += v * ad;
    }
  }
#pragma unroll
  for (int reg = 0; reg < 4; reg++) {
    float vs = ps_s[reg], vd = ps_d[reg];
    vs += __shfl_xor(vs, 8, 64); vs += __shfl_xor(vs, 4, 64);
    vs += __shfl_xor(vs, 2, 64); vs += __shfl_xor(vs, 1, 64);
    vd += __shfl_xor(vd, 8, 64); vd += __shfl_xor(vd, 4, 64);
    vd += __shfl_xor(vd, 2, 64); vd += __shfl_xor(vd, 1, 64);
    int row = row0 + quad * 4 + reg;
    if (qr == 0 && row < NN) { a_src2[row] = vs; a_dst2[row] = vd; }
  }
}

// ---------- Layer-2 aggregation: quarter-wave, 2 edges/quarter in flight --
__global__ __launch_bounds__(256) void k_agg2(const int* __restrict__ rowp,
    const int* __restrict__ col, const float* __restrict__ a_src2,
    const float* __restrict__ a_dst2, const u16* __restrict__ h2b,
    const float* __restrict__ b2, float* __restrict__ out) {
  int node = (blockIdx.x * 256 + threadIdx.x) >> 6;
  if (node >= NN) return;
  const int lane = threadIdx.x & 63;
  const int q = lane >> 4;
  const int ql = lane & 15;     // owns cols 4*ql .. 4*ql+3
  const float ad = a_dst2[node];
  float num[4] = {};
  float den = 0.f;
  const int beg = rowp[node], end = rowp[node + 1];
  int e = beg + q;
  int s0 = (e < end) ? col[e] : 0;
  int s1 = (e + 4 < end) ? col[e + 4] : 0;
  while (e + 4 < end) {
    const int cs0 = s0, cs1 = s1;
    if (e + 8 < end) s0 = col[e + 8];
    if (e + 12 < end) s1 = col[e + 12];
    float w0 = __expf(lrelu(a_src2[cs0] + ad));
    float w1 = __expf(lrelu(a_src2[cs1] + ad));
    uint2 hv0 = ((const uint2*)(h2b + (size_t)cs0 * RP))[ql];
    uint2 hv1 = ((const uint2*)(h2b + (size_t)cs1 * RP))[ql];
    den += w0 + w1;
    num[0] += w0 * bfl(hv0.x) + w1 * bfl(hv1.x);
    num[1] += w0 * bfh(hv0.x) + w1 * bfh(hv1.x);
    num[2] += w0 * bfl(hv0.y) + w1 * bfl(hv1.y);
    num[3] += w0 * bfh(hv0.y) + w1 * bfh(hv1.y);
    e += 8;
  }
  if (e < end) {
    float w0 = __expf(lrelu(a_src2[s0] + ad));
    uint2 hv0 = ((const uint2*)(h2b + (size_t)s0 * RP))[ql];
    den += w0;
    num[0] += w0 * bfl(hv0.x); num[1] += w0 * bfh(hv0.x);
    num[2] += w0 * bfl(hv0.y); num[3] += w0 * bfh(hv0.y);
  }
  den += __shfl_xor(den, 16, 64);
  den += __shfl_xor(den, 32, 64);
#pragma unroll
  for (int j = 0; j < 4; j++) {
    num[j] += __shfl_xor(num[j], 16, 64);
    num[j] += __shfl_xor(num[j], 32, 64);
  }
  if (q == 0) {
    const float inv = 1.f / (den + 1e-16f);
    const float4 b = ((const float4*)(b2 + ql * 4))[0];
    float4 o;
    o.x = num[0] * inv + b.x;
    o.y = num[1] * inv + b.y;
    o.z = num[2] * inv + b.z;
    o.w = num[3] * inv + b.w;
    ((float4*)(out + (size_t)node * RP + ql * 4))[0] = o;
  }
}

extern "C" void kernel_launch(void* const* d_in, const int* in_sizes, int n_in,
                              void* d_out, int out_size, void* d_ws, size_t ws_size,
                              hipStream_t stream) {
  const float* x   = (const float*)d_in[0];
  const float* W1  = (const float*)d_in[1];
  const float* a1s = (const float*)d_in[2];
  const float* a1d = (const float*)d_in[3];
  const float* b1  = (const float*)d_in[4];
  const float* W2  = (const float*)d_in[5];
  const float* a2s = (const float*)d_in[6];
  const float* a2d = (const float*)d_in[7];
  const float* b2  = (const float*)d_in[8];
  const int*   es  = (const int*)d_in[9];
  const int*   ed  = es + EE;
  float* out = (float*)d_out;

  // workspace layout
  u16*   h1b    = (u16*)d_ws;                        // N*256 bf16 (reused as h2b)
  u16*   x2b    = h1b + (size_t)NN * HID;            // N*256 bf16
  float* asrc1  = (float*)(x2b + (size_t)NN * HID);  // N*8
  float* adst1  = asrc1 + (size_t)NN * NH;           // N*8
  int*   rowp   = (int*)(adst1 + (size_t)NN * NH);   // N+1
  int*   col    = rowp + NN + 1;                     // ET
  int*   Gh     = col + ET;                          // EDGE_BLOCKS*256
  int*   ebuf   = Gh + EDGE_BLOCKS * 256;            // ET packed edges
  int*   btot   = ebuf + ET;                         // 256
  int*   bstart = btot + 256;                        // 256
  u16*   Bbuf   = (u16*)(bstart + 256);              // 128*256 bf16 frag-major
  u16*   Bbuf2  = Bbuf + (size_t)EMB * HID;          // 256*64 bf16 frag-major
  u16*   h2b    = h1b;
  float* asrc2  = asrc1;
  float* adst2  = adst1;

  // W prep + edge bucket histograms
  k_pre<<<W1P_BLOCKS + W2P_BLOCKS + EDGE_BLOCKS, 256, 0, stream>>>(
      W1, Bbuf, W2, Bbuf2, ed, Gh);

  // MFMA GEMM1 fused with the Gh column-scan (rides free under the GEMM)
  k_g1<<<G1M_BLOCKS + NBUCK, 256, 0, stream>>>(
      x, Bbuf, a1s, a1d, h1b, asrc1, adst1, Gh, btot);

  k_bstart<<<1, 256, 0, stream>>>(btot, bstart);
  k_bscatter<<<EDGE_BLOCKS, 256, 0, stream>>>(es, ed, Gh, bstart, ebuf);
  k_csr<<<NBUCK, 256, 0, stream>>>(ebuf, bstart, rowp, col);

  k_agg1<<<(NN * 64 + 255) / 256, 256, 0, stream>>>(rowp, col, asrc1, adst1, h1b, b1, x2b);
  k_gemm2m<<<G2M_BLOCKS, 256, 0, stream>>>(x2b, Bbuf2, a2s, a2d, h2b, asrc2, adst2);
  k_agg2<<<(NN * 64 + 255) / 256, 256, 0, stream>>>(rowp, col, asrc2, adst2, h2b, b2, out);
}

// Round 10
// 216.574 us; speedup vs baseline: 1.0575x; 1.0361x over previous
//
#include <hip/hip_runtime.h>

#define NN 50000      // nodes
#define EE 500000     // raw edges
#define ET 550000     // edges + self loops
#define EMB 128
#define HID 256
#define NH 8
#define RP 64
#define G1M_BLOCKS (NN / 16)                       // 3125 MFMA m-tiles
#define EDGE_BLOCKS ((ET + 255) / 256)             // 2149 edge blocks
#define NBUCK 196                                  // dst>>8 buckets
#define W1P_BLOCKS 16
#define W2P_BLOCKS 8
#define AGG_BLOCKS (NN / 16)                       // 3125 fused agg1+gemm2 blocks
#define XT_STRIDE 264                              // padded LDS row (bf16 units)

typedef unsigned short u16;
typedef __attribute__((ext_vector_type(8))) short bf16x8;
typedef __attribute__((ext_vector_type(4))) float f32x4;

__device__ __forceinline__ float lrelu(float v) { return v > 0.f ? v : 0.2f * v; }
__device__ __forceinline__ float elu(float v) { return v > 0.f ? v : __expf(v) - 1.f; }
__device__ __forceinline__ u16 f2bf(float f) {
  unsigned int u = __float_as_uint(f);
  u += 0x7FFFu + ((u >> 16) & 1u);
  return (u16)(u >> 16);
}
__device__ __forceinline__ float bfl(unsigned int u) { return __uint_as_float(u << 16); }
__device__ __forceinline__ float bfh(unsigned int u) { return __uint_as_float(u & 0xFFFF0000u); }

// ---------- k_pre: W1 prep | W2 prep | edge bucket histograms -------------
__global__ __launch_bounds__(256) void k_pre(const float* __restrict__ W1,
    u16* __restrict__ Bbuf, const float* __restrict__ W2, u16* __restrict__ Bbuf2,
    const int* __restrict__ ed, int* __restrict__ Gh) {
  const int tid = threadIdx.x;
  const int b = blockIdx.x;
  if (b >= W1P_BLOCKS + W2P_BLOCKS) {
    __shared__ int cnt[256];
    const int blk = b - W1P_BLOCKS - W2P_BLOCKS;
    cnt[tid] = 0;
    __syncthreads();
    int i = blk * 256 + tid;
    if (i < ET) {
      int d = (i < EE) ? ed[i] : i - EE;
      atomicAdd(&cnt[d >> 8], 1);
    }
    __syncthreads();
    Gh[blk * 256 + tid] = cnt[tid];
    return;
  }
  const int l = tid & 63;
  const int quad = l >> 4, qr = l & 15;
  if (b < W1P_BLOCKS) {               // W1 -> bf16 B-frags (kt<4, nt<16)
    const int tile = b * 4 + (tid >> 6);
    const int kt = tile >> 4, nt = tile & 15;
    const float* src = W1 + (size_t)(kt * 32 + quad * 8) * HID + nt * 16 + qr;
    unsigned int p[4];
#pragma unroll
    for (int jp = 0; jp < 4; jp++) {
      u16 lo = f2bf(src[(2 * jp + 0) * HID]);
      u16 hi = f2bf(src[(2 * jp + 1) * HID]);
      p[jp] = (unsigned int)lo | ((unsigned int)hi << 16);
    }
    ((uint4*)Bbuf)[tile * 64 + l] = (uint4){p[0], p[1], p[2], p[3]};
    return;
  }
  // W2 -> bf16 B-frags (kt<8, nt<4)
  const int tile = (b - W1P_BLOCKS) * 4 + (tid >> 6);
  const int kt = tile >> 2, nt = tile & 3;
  const float* src = W2 + (size_t)(kt * 32 + quad * 8) * RP + nt * 16 + qr;
  unsigned int p[4];
#pragma unroll
  for (int jp = 0; jp < 4; jp++) {
    u16 lo = f2bf(src[(2 * jp + 0) * RP]);
    u16 hi = f2bf(src[(2 * jp + 1) * RP]);
    p[jp] = (unsigned int)lo | ((unsigned int)hi << 16);
  }
  ((uint4*)Bbuf2)[tile * 64 + l] = (uint4){p[0], p[1], p[2], p[3]};
}

// ---------- GEMM1 MFMA + fused per-bucket column scan of Gh ---------------
__global__ __launch_bounds__(256) void k_g1(const float* __restrict__ x,
    const u16* __restrict__ Bbuf, const float* __restrict__ asw,
    const float* __restrict__ adw, u16* __restrict__ h1b,
    float* __restrict__ a_src, float* __restrict__ a_dst,
    int* __restrict__ Gh, int* __restrict__ btot) {
  const int tid = threadIdx.x;
  if (blockIdx.x >= G1M_BLOCKS) {
    __shared__ int s[256];
    const int t = tid;
    const int b = blockIdx.x - G1M_BLOCKS;
    int off = 0;
    for (int k0 = 0; k0 < EDGE_BLOCKS; k0 += 256) {
      int k = k0 + t;
      int v = (k < EDGE_BLOCKS) ? Gh[k * 256 + b] : 0;
      s[t] = v;
      __syncthreads();
      for (int o = 1; o < 256; o <<= 1) {
        int y = (t >= o) ? s[t - o] : 0;
        __syncthreads();
        s[t] += y;
        __syncthreads();
      }
      if (k < EDGE_BLOCKS) Gh[k * 256 + b] = off + s[t] - v;
      int tot = s[255];
      __syncthreads();
      off += tot;
    }
    if (t == 0) btot[b] = off;
    return;
  }
  const int w = tid >> 6, l = tid & 63;
  const int quad = l >> 4, qr = l & 15;
  const int node0 = blockIdx.x * 16;

  bf16x8 A[4];
  const float4* X4 = (const float4*)(x + (size_t)(node0 + qr) * EMB);
#pragma unroll
  for (int kt = 0; kt < 4; kt++) {
    float4 a0 = X4[kt * 8 + quad * 2];
    float4 a1 = X4[kt * 8 + quad * 2 + 1];
    A[kt][0] = (short)f2bf(a0.x); A[kt][1] = (short)f2bf(a0.y);
    A[kt][2] = (short)f2bf(a0.z); A[kt][3] = (short)f2bf(a0.w);
    A[kt][4] = (short)f2bf(a1.x); A[kt][5] = (short)f2bf(a1.y);
    A[kt][6] = (short)f2bf(a1.z); A[kt][7] = (short)f2bf(a1.w);
  }

  f32x4 acc[4];
  const bf16x8* Bf = (const bf16x8*)Bbuf;
#pragma unroll
  for (int nt = 0; nt < 4; nt++) {
    acc[nt] = (f32x4){0.f, 0.f, 0.f, 0.f};
    const int ntg = w * 4 + nt;
#pragma unroll
    for (int kt = 0; kt < 4; kt++) {
      bf16x8 B = Bf[(kt * 16 + ntg) * 64 + l];
      acc[nt] = __builtin_amdgcn_mfma_f32_16x16x32_bf16(A[kt], B, acc[nt], 0, 0, 0);
    }
  }

  float ps_s[4][2] = {};
  float ps_d[4][2] = {};
#pragma unroll
  for (int nt = 0; nt < 4; nt++) {
    const int colg = w * 64 + nt * 16 + qr;
    const float as = asw[colg], ad = adw[colg];
    const int hh = nt >> 1;
#pragma unroll
    for (int reg = 0; reg < 4; reg++) {
      float v = acc[nt][reg];
      int row = node0 + quad * 4 + reg;
      h1b[(size_t)row * HID + colg] = f2bf(v);
      ps_s[reg][hh] += v * as;
      ps_d[reg][hh] += v * ad;
    }
  }
#pragma unroll
  for (int reg = 0; reg < 4; reg++) {
#pragma unroll
    for (int hh = 0; hh < 2; hh++) {
      float vs = ps_s[reg][hh], vd = ps_d[reg][hh];
      vs += __shfl_xor(vs, 8, 64); vs += __shfl_xor(vs, 4, 64);
      vs += __shfl_xor(vs, 2, 64); vs += __shfl_xor(vs, 1, 64);
      vd += __shfl_xor(vd, 8, 64); vd += __shfl_xor(vd, 4, 64);
      vd += __shfl_xor(vd, 2, 64); vd += __shfl_xor(vd, 1, 64);
      if (qr == 0) {
        int row = node0 + quad * 4 + reg;
        int head = 2 * w + hh;
        a_src[row * NH + head] = vs;
        a_dst[row * NH + head] = vd;
      }
    }
  }
}

// ---------- k_bscatter: edge scatter into bucket order (local bstart) -----
__global__ __launch_bounds__(256) void k_bscatter(const int* __restrict__ es,
    const int* __restrict__ ed, const int* __restrict__ Gh,
    const int* __restrict__ btot, int* __restrict__ ebuf) {
  __shared__ int cnt[256];
  __shared__ int bst[256];
  const int tid = threadIdx.x;
  const int blk = blockIdx.x;
  // local exclusive scan of btot -> bucket starts
  int v = (tid < NBUCK) ? btot[tid] : 0;
  bst[tid] = v;
  cnt[tid] = 0;
  __syncthreads();
  for (int o = 1; o < 256; o <<= 1) {
    int y = (tid >= o) ? bst[tid - o] : 0;
    __syncthreads();
    bst[tid] += y;
    __syncthreads();
  }
  bst[tid] -= v;   // exclusive
  __syncthreads();
  int i = blk * 256 + tid;
  if (i < ET) {
    int s, d;
    if (i < EE) { s = es[i]; d = ed[i]; } else { s = d = i - EE; }
    int bkt = d >> 8;
    int r = atomicAdd(&cnt[bkt], 1);
    int pos = bst[bkt] + Gh[blk * 256 + bkt] + r;
    ebuf[pos] = ((d & 255) << 16) | s;
  }
}

// ---------- k_csr: per-bucket CSR finalize (local bstart) -----------------
__global__ __launch_bounds__(256) void k_csr(const int* __restrict__ ebuf,
    const int* __restrict__ btot, int* __restrict__ rowp, int* __restrict__ col) {
  __shared__ int cnt[256];
  __shared__ int cur[256];
  __shared__ int bst[256];
  const int t = threadIdx.x;
  const int b = blockIdx.x;
  // local exclusive scan of btot
  int bv = (t < NBUCK) ? btot[t] : 0;
  bst[t] = bv;
  cnt[t] = 0;
  __syncthreads();
  for (int o = 1; o < 256; o <<= 1) {
    int y = (t >= o) ? bst[t - o] : 0;
    __syncthreads();
    bst[t] += y;
    __syncthreads();
  }
  __syncthreads();
  const int segs = bst[b] - btot[b] + 0;           // exclusive prefix at b
  const int segs_ex = bst[b] - ((b < NBUCK) ? btot[b] : 0);
  const int sege = bst[b];                          // inclusive prefix at b
  (void)segs;
  for (int i = segs_ex + t; i < sege; i += 256)
    atomicAdd(&cnt[(ebuf[i] >> 16) & 255], 1);
  __syncthreads();
  int v = cnt[t];
  cur[t] = v;
  __syncthreads();
  for (int o = 1; o < 256; o <<= 1) {
    int y = (t >= o) ? cur[t - o] : 0;
    __syncthreads();
    cur[t] += y;
    __syncthreads();
  }
  int base = segs_ex + cur[t] - v;
  int node = b * 256 + t;
  if (node <= NN) rowp[node] = base;
  cur[t] = base;
  __syncthreads();
  for (int i = segs_ex + t; i < sege; i += 256) {
    int p = ebuf[i];
    int pos = atomicAdd(&cur[(p >> 16) & 255], 1);
    col[pos] = p & 0xFFFF;
  }
  if (b == 0 && t == 0) rowp[NN] = ET;
}

// ---------- fused Layer-1 aggregation + GEMM2 MFMA ------------------------
// block = 16 nodes; wave w aggregates nodes node0+4w..+3 (half-wave edge loop),
// stores x2 rows (bf16) to LDS tile; barrier; wave w does 16x16 MFMA gemm2
// for cols [16w,16w+16), stores h2b + cross-wave att-dot partials in LDS.
__global__ __launch_bounds__(256) void k_agg1g2(const int* __restrict__ rowp,
    const int* __restrict__ col, const float* __restrict__ a_src,
    const float* __restrict__ a_dst, const u16* __restrict__ h1b,
    const float* __restrict__ b1, const u16* __restrict__ Bbuf2,
    const float* __restrict__ asw2, const float* __restrict__ adw2,
    u16* __restrict__ h2b, float* __restrict__ a_src2, float* __restrict__ a_dst2) {
  __shared__ __align__(16) u16 xtile[16][XT_STRIDE];
  __shared__ float sp_s[4][16];
  __shared__ float sp_d[4][16];
  const int tid = threadIdx.x;
  const int w = tid >> 6, lane = tid & 63;
  const int half = lane >> 5;
  const int hl = lane & 31;     // owns cols 8*hl .. 8*hl+7
  const int h = hl >> 2;        // head
  const int node0 = blockIdx.x * 16;

  // ---- phase 1: aggregate 4 nodes per wave ----
  for (int nd = 0; nd < 4; nd++) {
    const int node = node0 + w * 4 + nd;
    const float ad = a_dst[node * NH + h];
    float num[8] = {};
    float den = 0.f;
    const int beg = rowp[node], end = rowp[node + 1];
    int e = beg + half;
    int s0 = (e < end) ? col[e] : 0;
    int s1 = (e + 2 < end) ? col[e + 2] : 0;
    while (e + 2 < end) {
      const int cs0 = s0, cs1 = s1;
      if (e + 4 < end) s0 = col[e + 4];
      if (e + 6 < end) s1 = col[e + 6];
      float w0 = __expf(lrelu(a_src[cs0 * NH + h] + ad));
      float w1 = __expf(lrelu(a_src[cs1 * NH + h] + ad));
      uint4 hv0 = ((const uint4*)(h1b + (size_t)cs0 * HID))[hl];
      uint4 hv1 = ((const uint4*)(h1b + (size_t)cs1 * HID))[hl];
      den += w0 + w1;
      num[0] += w0 * bfl(hv0.x) + w1 * bfl(hv1.x);
      num[1] += w0 * bfh(hv0.x) + w1 * bfh(hv1.x);
      num[2] += w0 * bfl(hv0.y) + w1 * bfl(hv1.y);
      num[3] += w0 * bfh(hv0.y) + w1 * bfh(hv1.y);
      num[4] += w0 * bfl(hv0.z) + w1 * bfl(hv1.z);
      num[5] += w0 * bfh(hv0.z) + w1 * bfh(hv1.z);
      num[6] += w0 * bfl(hv0.w) + w1 * bfl(hv1.w);
      num[7] += w0 * bfh(hv0.w) + w1 * bfh(hv1.w);
      e += 4;
    }
    if (e < end) {
      float w0 = __expf(lrelu(a_src[s0 * NH + h] + ad));
      uint4 hv0 = ((const uint4*)(h1b + (size_t)s0 * HID))[hl];
      den += w0;
      num[0] += w0 * bfl(hv0.x); num[1] += w0 * bfh(hv0.x);
      num[2] += w0 * bfl(hv0.y); num[3] += w0 * bfh(hv0.y);
      num[4] += w0 * bfl(hv0.z); num[5] += w0 * bfh(hv0.z);
      num[6] += w0 * bfl(hv0.w); num[7] += w0 * bfh(hv0.w);
    }
    den += __shfl_xor(den, 32, 64);
#pragma unroll
    for (int j = 0; j < 8; j++) num[j] += __shfl_xor(num[j], 32, 64);
    if (half == 0) {
      const float inv = 1.f / (den + 1e-16f);
      const float4 b0 = ((const float4*)(b1 + hl * 8))[0];
      const float4 b1v = ((const float4*)(b1 + hl * 8))[1];
      float o[8];
      o[0] = elu(num[0] * inv + b0.x);
      o[1] = elu(num[1] * inv + b0.y);
      o[2] = elu(num[2] * inv + b0.z);
      o[3] = elu(num[3] * inv + b0.w);
      o[4] = elu(num[4] * inv + b1v.x);
      o[5] = elu(num[5] * inv + b1v.y);
      o[6] = elu(num[6] * inv + b1v.z);
      o[7] = elu(num[7] * inv + b1v.w);
      unsigned int dw[4];
#pragma unroll
      for (int jp = 0; jp < 4; jp++)
        dw[jp] = (unsigned int)f2bf(o[2 * jp]) | ((unsigned int)f2bf(o[2 * jp + 1]) << 16);
      *((uint4*)&xtile[w * 4 + nd][hl * 8]) = (uint4){dw[0], dw[1], dw[2], dw[3]};
    }
  }
  __syncthreads();

  // ---- phase 2: gemm2 for cols [16w, 16w+16) over the 16-node tile ----
  const int quad = lane >> 4, qr = lane & 15;
  f32x4 acc = (f32x4){0.f, 0.f, 0.f, 0.f};
  const bf16x8* Bf = (const bf16x8*)Bbuf2;
#pragma unroll
  for (int kt = 0; kt < 8; kt++) {
    bf16x8 Afrag = *((const bf16x8*)&xtile[qr][kt * 32 + quad * 8]);
    bf16x8 B = Bf[(kt * 4 + w) * 64 + lane];
    acc = __builtin_amdgcn_mfma_f32_16x16x32_bf16(Afrag, B, acc, 0, 0, 0);
  }
  const int colg = w * 16 + qr;
  const float as2 = asw2[colg], ad2 = adw2[colg];
  float vs_p[4], vd_p[4];
#pragma unroll
  for (int reg = 0; reg < 4; reg++) {
    float v = acc[reg];
    int row = quad * 4 + reg;
    h2b[(size_t)(node0 + row) * RP + colg] = f2bf(v);
    vs_p[reg] = v * as2;
    vd_p[reg] = v * ad2;
  }
#pragma unroll
  for (int reg = 0; reg < 4; reg++) {
    float vs = vs_p[reg], vd = vd_p[reg];
    vs += __shfl_xor(vs, 8, 64); vs += __shfl_xor(vs, 4, 64);
    vs += __shfl_xor(vs, 2, 64); vs += __shfl_xor(vs, 1, 64);
    vd += __shfl_xor(vd, 8, 64); vd += __shfl_xor(vd, 4, 64);
    vd += __shfl_xor(vd, 2, 64); vd += __shfl_xor(vd, 1, 64);
    if (qr == 0) {
      sp_s[w][quad * 4 + reg] = vs;
      sp_d[w][quad * 4 + reg] = vd;
    }
  }
  __syncthreads();
  if (tid < 16) {
    a_src2[node0 + tid] = sp_s[0][tid] + sp_s[1][tid] + sp_s[2][tid] + sp_s[3][tid];
    a_dst2[node0 + tid] = sp_d[0][tid] + sp_d[1][tid] + sp_d[2][tid] + sp_d[3][tid];
  }
}

// ---------- Layer-2 aggregation: quarter-wave, 2 edges/quarter in flight --
__global__ __launch_bounds__(256) void k_agg2(const int* __restrict__ rowp,
    const int* __restrict__ col, const float* __restrict__ a_src2,
    const float* __restrict__ a_dst2, const u16* __restrict__ h2b,
    const float* __restrict__ b2, float* __restrict__ out) {
  int node = (blockIdx.x * 256 + threadIdx.x) >> 6;
  if (node >= NN) return;
  const int lane = threadIdx.x & 63;
  const int q = lane >> 4;
  const int ql = lane & 15;     // owns cols 4*ql .. 4*ql+3
  const float ad = a_dst2[node];
  float num[4] = {};
  float den = 0.f;
  const int beg = rowp[node], end = rowp[node + 1];
  int e = beg + q;
  int s0 = (e < end) ? col[e] : 0;
  int s1 = (e + 4 < end) ? col[e + 4] : 0;
  while (e + 4 < end) {
    const int cs0 = s0, cs1 = s1;
    if (e + 8 < end) s0 = col[e + 8];
    if (e + 12 < end) s1 = col[e + 12];
    float w0 = __expf(lrelu(a_src2[cs0] + ad));
    float w1 = __expf(lrelu(a_src2[cs1] + ad));
    uint2 hv0 = ((const uint2*)(h2b + (size_t)cs0 * RP))[ql];
    uint2 hv1 = ((const uint2*)(h2b + (size_t)cs1 * RP))[ql];
    den += w0 + w1;
    num[0] += w0 * bfl(hv0.x) + w1 * bfl(hv1.x);
    num[1] += w0 * bfh(hv0.x) + w1 * bfh(hv1.x);
    num[2] += w0 * bfl(hv0.y) + w1 * bfl(hv1.y);
    num[3] += w0 * bfh(hv0.y) + w1 * bfh(hv1.y);
    e += 8;
  }
  if (e < end) {
    float w0 = __expf(lrelu(a_src2[s0] + ad));
    uint2 hv0 = ((const uint2*)(h2b + (size_t)s0 * RP))[ql];
    den += w0;
    num[0] += w0 * bfl(hv0.x); num[1] += w0 * bfh(hv0.x);
    num[2] += w0 * bfl(hv0.y); num[3] += w0 * bfh(hv0.y);
  }
  den += __shfl_xor(den, 16, 64);
  den += __shfl_xor(den, 32, 64);
#pragma unroll
  for (int j = 0; j < 4; j++) {
    num[j] += __shfl_xor(num[j], 16, 64);
    num[j] += __shfl_xor(num[j], 32, 64);
  }
  if (q == 0) {
    const float inv = 1.f / (den + 1e-16f);
    const float4 b = ((const float4*)(b2 + ql * 4))[0];
    float4 o;
    o.x = num[0] * inv + b.x;
    o.y = num[1] * inv + b.y;
    o.z = num[2] * inv + b.z;
    o.w = num[3] * inv + b.w;
    ((float4*)(out + (size_t)node * RP + ql * 4))[0] = o;
  }
}

extern "C" void kernel_launch(void* const* d_in, const int* in_sizes, int n_in,
                              void* d_out, int out_size, void* d_ws, size_t ws_size,
                              hipStream_t stream) {
  const float* x   = (const float*)d_in[0];
  const float* W1  = (const float*)d_in[1];
  const float* a1s = (const float*)d_in[2];
  const float* a1d = (const float*)d_in[3];
  const float* b1  = (const float*)d_in[4];
  const float* W2  = (const float*)d_in[5];
  const float* a2s = (const float*)d_in[6];
  const float* a2d = (const float*)d_in[7];
  const float* b2  = (const float*)d_in[8];
  const int*   es  = (const int*)d_in[9];
  const int*   ed  = es + EE;
  float* out = (float*)d_out;

  // workspace layout (h2b must NOT alias h1b: fused kernel overlaps phases)
  u16*   h1b   = (u16*)d_ws;                        // N*256 bf16
  u16*   h2b   = h1b + (size_t)NN * HID;            // N*64 bf16
  float* asrc1 = (float*)(h2b + (size_t)NN * RP);   // N*8
  float* adst1 = asrc1 + (size_t)NN * NH;           // N*8
  float* asrc2 = adst1 + (size_t)NN * NH;           // N
  float* adst2 = asrc2 + NN;                        // N
  int*   rowp  = (int*)(adst2 + NN);                // N+1
  int*   col   = rowp + NN + 1;                     // ET
  int*   Gh    = col + ET;                          // EDGE_BLOCKS*256
  int*   ebuf  = Gh + EDGE_BLOCKS * 256;            // ET packed edges
  int*   btot  = ebuf + ET;                         // 256
  u16*   Bbuf  = (u16*)(btot + 256);                // 128*256 bf16 frag-major
  u16*   Bbuf2 = Bbuf + (size_t)EMB * HID;          // 256*64 bf16 frag-major

  // W prep + edge bucket histograms
  k_pre<<<W1P_BLOCKS + W2P_BLOCKS + EDGE_BLOCKS, 256, 0, stream>>>(
      W1, Bbuf, W2, Bbuf2, ed, Gh);

  // MFMA GEMM1 fused with the Gh column-scan
  k_g1<<<G1M_BLOCKS + NBUCK, 256, 0, stream>>>(
      x, Bbuf, a1s, a1d, h1b, asrc1, adst1, Gh, btot);

  k_bscatter<<<EDGE_BLOCKS, 256, 0, stream>>>(es, ed, Gh, btot, ebuf);
  k_csr<<<NBUCK, 256, 0, stream>>>(ebuf, btot, rowp, col);

  // fused agg1 + gemm2 (x2 never touches global; h2b separate from h1b)
  k_agg1g2<<<AGG_BLOCKS, 256, 0, stream>>>(rowp, col, asrc1, adst1, h1b, b1,
                                           Bbuf2, a2s, a2d, h2b, asrc2, adst2);

  k_agg2<<<(NN * 64 + 255) / 256, 256, 0, stream>>>(rowp, col, asrc2, adst2, h2b, b2, out);
}

// Round 11
// 210.634 us; speedup vs baseline: 1.0874x; 1.0282x over previous
//
#include <hip/hip_runtime.h>

#define NN 50000      // nodes
#define EE 500000     // raw edges
#define ET 550000     // edges + self loops
#define EMB 128
#define HID 256
#define NH 8
#define RP 64
#define G1M_BLOCKS (NN / 16)                       // 3125 MFMA m-tiles
#define CH 2048                                    // edges per hist/scatter chunk
#define HBLK ((ET + CH - 1) / CH)                  // 269 chunk blocks
#define NBUCK 196                                  // dst>>8 buckets
#define W1P_BLOCKS 16
#define W2P_BLOCKS 8
#define AGG_BLOCKS (NN / 16)                       // 3125 fused agg1+gemm2 blocks
#define XT_STRIDE 264                              // padded LDS row (bf16 units)

typedef unsigned short u16;
typedef __attribute__((ext_vector_type(8))) short bf16x8;
typedef __attribute__((ext_vector_type(4))) float f32x4;

__device__ __forceinline__ float lrelu(float v) { return v > 0.f ? v : 0.2f * v; }
__device__ __forceinline__ float elu(float v) { return v > 0.f ? v : __expf(v) - 1.f; }
__device__ __forceinline__ u16 f2bf(float f) {
  unsigned int u = __float_as_uint(f);
  u += 0x7FFFu + ((u >> 16) & 1u);
  return (u16)(u >> 16);
}
__device__ __forceinline__ float bfl(unsigned int u) { return __uint_as_float(u << 16); }
__device__ __forceinline__ float bfh(unsigned int u) { return __uint_as_float(u & 0xFFFF0000u); }

// ---------- k_pre: W1 prep | W2 prep | chunked edge bucket histograms -----
__global__ __launch_bounds__(256) void k_pre(const float* __restrict__ W1,
    u16* __restrict__ Bbuf, const float* __restrict__ W2, u16* __restrict__ Bbuf2,
    const int* __restrict__ ed, int* __restrict__ Gh) {
  const int tid = threadIdx.x;
  const int b = blockIdx.x;
  if (b >= W1P_BLOCKS + W2P_BLOCKS) {
    __shared__ int cnt[256];
    const int blk = b - W1P_BLOCKS - W2P_BLOCKS;
    cnt[tid] = 0;
    __syncthreads();
#pragma unroll
    for (int it = 0; it < CH / 256; it++) {
      int i = blk * CH + it * 256 + tid;
      if (i < ET) {
        int d = (i < EE) ? ed[i] : i - EE;
        atomicAdd(&cnt[d >> 8], 1);
      }
    }
    __syncthreads();
    Gh[blk * 256 + tid] = cnt[tid];
    return;
  }
  const int l = tid & 63;
  const int quad = l >> 4, qr = l & 15;
  if (b < W1P_BLOCKS) {               // W1 -> bf16 B-frags (kt<4, nt<16)
    const int tile = b * 4 + (tid >> 6);
    const int kt = tile >> 4, nt = tile & 15;
    const float* src = W1 + (size_t)(kt * 32 + quad * 8) * HID + nt * 16 + qr;
    unsigned int p[4];
#pragma unroll
    for (int jp = 0; jp < 4; jp++) {
      u16 lo = f2bf(src[(2 * jp + 0) * HID]);
      u16 hi = f2bf(src[(2 * jp + 1) * HID]);
      p[jp] = (unsigned int)lo | ((unsigned int)hi << 16);
    }
    ((uint4*)Bbuf)[tile * 64 + l] = (uint4){p[0], p[1], p[2], p[3]};
    return;
  }
  // W2 -> bf16 B-frags (kt<8, nt<4)
  const int tile = (b - W1P_BLOCKS) * 4 + (tid >> 6);
  const int kt = tile >> 2, nt = tile & 3;
  const float* src = W2 + (size_t)(kt * 32 + quad * 8) * RP + nt * 16 + qr;
  unsigned int p[4];
#pragma unroll
  for (int jp = 0; jp < 4; jp++) {
    u16 lo = f2bf(src[(2 * jp + 0) * RP]);
    u16 hi = f2bf(src[(2 * jp + 1) * RP]);
    p[jp] = (unsigned int)lo | ((unsigned int)hi << 16);
  }
  ((uint4*)Bbuf2)[tile * 64 + l] = (uint4){p[0], p[1], p[2], p[3]};
}

// ---------- GEMM1 MFMA + fused per-bucket column scan of Gh ---------------
__global__ __launch_bounds__(256) void k_g1(const float* __restrict__ x,
    const u16* __restrict__ Bbuf, const float* __restrict__ asw,
    const float* __restrict__ adw, u16* __restrict__ h1b,
    float* __restrict__ a_src, float* __restrict__ a_dst,
    int* __restrict__ Gh, int* __restrict__ btot) {
  const int tid = threadIdx.x;
  if (blockIdx.x >= G1M_BLOCKS) {
    __shared__ int s[256];
    const int t = tid;
    const int b = blockIdx.x - G1M_BLOCKS;
    int off = 0;
    for (int k0 = 0; k0 < HBLK; k0 += 256) {
      int k = k0 + t;
      int v = (k < HBLK) ? Gh[k * 256 + b] : 0;
      s[t] = v;
      __syncthreads();
      for (int o = 1; o < 256; o <<= 1) {
        int y = (t >= o) ? s[t - o] : 0;
        __syncthreads();
        s[t] += y;
        __syncthreads();
      }
      if (k < HBLK) Gh[k * 256 + b] = off + s[t] - v;
      int tot = s[255];
      __syncthreads();
      off += tot;
    }
    if (t == 0) btot[b] = off;
    return;
  }
  const int w = tid >> 6, l = tid & 63;
  const int quad = l >> 4, qr = l & 15;
  const int node0 = blockIdx.x * 16;

  bf16x8 A[4];
  const float4* X4 = (const float4*)(x + (size_t)(node0 + qr) * EMB);
#pragma unroll
  for (int kt = 0; kt < 4; kt++) {
    float4 a0 = X4[kt * 8 + quad * 2];
    float4 a1 = X4[kt * 8 + quad * 2 + 1];
    A[kt][0] = (short)f2bf(a0.x); A[kt][1] = (short)f2bf(a0.y);
    A[kt][2] = (short)f2bf(a0.z); A[kt][3] = (short)f2bf(a0.w);
    A[kt][4] = (short)f2bf(a1.x); A[kt][5] = (short)f2bf(a1.y);
    A[kt][6] = (short)f2bf(a1.z); A[kt][7] = (short)f2bf(a1.w);
  }

  f32x4 acc[4];
  const bf16x8* Bf = (const bf16x8*)Bbuf;
#pragma unroll
  for (int nt = 0; nt < 4; nt++) {
    acc[nt] = (f32x4){0.f, 0.f, 0.f, 0.f};
    const int ntg = w * 4 + nt;
#pragma unroll
    for (int kt = 0; kt < 4; kt++) {
      bf16x8 B = Bf[(kt * 16 + ntg) * 64 + l];
      acc[nt] = __builtin_amdgcn_mfma_f32_16x16x32_bf16(A[kt], B, acc[nt], 0, 0, 0);
    }
  }

  float ps_s[4][2] = {};
  float ps_d[4][2] = {};
#pragma unroll
  for (int nt = 0; nt < 4; nt++) {
    const int colg = w * 64 + nt * 16 + qr;
    const float as = asw[colg], ad = adw[colg];
    const int hh = nt >> 1;
#pragma unroll
    for (int reg = 0; reg < 4; reg++) {
      float v = acc[nt][reg];
      int row = node0 + quad * 4 + reg;
      h1b[(size_t)row * HID + colg] = f2bf(v);
      ps_s[reg][hh] += v * as;
      ps_d[reg][hh] += v * ad;
    }
  }
#pragma unroll
  for (int reg = 0; reg < 4; reg++) {
#pragma unroll
    for (int hh = 0; hh < 2; hh++) {
      float vs = ps_s[reg][hh], vd = ps_d[reg][hh];
      vs += __shfl_xor(vs, 8, 64); vs += __shfl_xor(vs, 4, 64);
      vs += __shfl_xor(vs, 2, 64); vs += __shfl_xor(vs, 1, 64);
      vd += __shfl_xor(vd, 8, 64); vd += __shfl_xor(vd, 4, 64);
      vd += __shfl_xor(vd, 2, 64); vd += __shfl_xor(vd, 1, 64);
      if (qr == 0) {
        int row = node0 + quad * 4 + reg;
        int head = 2 * w + hh;
        a_src[row * NH + head] = vs;
        a_dst[row * NH + head] = vd;
      }
    }
  }
}

// ---------- k_bscatter: chunked edge scatter into bucket order ------------
__global__ __launch_bounds__(256) void k_bscatter(const int* __restrict__ es,
    const int* __restrict__ ed, const int* __restrict__ Gh,
    const int* __restrict__ btot, int* __restrict__ ebuf) {
  __shared__ int cnt[256];
  __shared__ int bst[256];
  const int tid = threadIdx.x;
  const int blk = blockIdx.x;
  // local exclusive scan of btot -> bucket starts
  int v = (tid < NBUCK) ? btot[tid] : 0;
  bst[tid] = v;
  cnt[tid] = 0;
  __syncthreads();
  for (int o = 1; o < 256; o <<= 1) {
    int y = (tid >= o) ? bst[tid - o] : 0;
    __syncthreads();
    bst[tid] += y;
    __syncthreads();
  }
  bst[tid] += Gh[blk * 256 + tid] - v;   // exclusive prefix + this block's offset
  __syncthreads();
#pragma unroll
  for (int it = 0; it < CH / 256; it++) {
    int i = blk * CH + it * 256 + tid;
    if (i < ET) {
      int s, d;
      if (i < EE) { s = es[i]; d = ed[i]; } else { s = d = i - EE; }
      int bkt = d >> 8;
      int r = atomicAdd(&cnt[bkt], 1);
      ebuf[bst[bkt] + r] = ((d & 255) << 16) | s;
    }
  }
}

// ---------- k_csr: per-bucket CSR finalize (local bstart) -----------------
__global__ __launch_bounds__(256) void k_csr(const int* __restrict__ ebuf,
    const int* __restrict__ btot, int* __restrict__ rowp, int* __restrict__ col) {
  __shared__ int cnt[256];
  __shared__ int cur[256];
  __shared__ int bst[256];
  const int t = threadIdx.x;
  const int b = blockIdx.x;
  int bv = (t < NBUCK) ? btot[t] : 0;
  bst[t] = bv;
  cnt[t] = 0;
  __syncthreads();
  for (int o = 1; o < 256; o <<= 1) {
    int y = (t >= o) ? bst[t - o] : 0;
    __syncthreads();
    bst[t] += y;
    __syncthreads();
  }
  __syncthreads();
  const int segs_ex = bst[b] - btot[b];   // exclusive prefix at b
  const int sege = bst[b];                // inclusive prefix at b
  for (int i = segs_ex + t; i < sege; i += 256)
    atomicAdd(&cnt[(ebuf[i] >> 16) & 255], 1);
  __syncthreads();
  int v = cnt[t];
  cur[t] = v;
  __syncthreads();
  for (int o = 1; o < 256; o <<= 1) {
    int y = (t >= o) ? cur[t - o] : 0;
    __syncthreads();
    cur[t] += y;
    __syncthreads();
  }
  int base = segs_ex + cur[t] - v;
  int node = b * 256 + t;
  if (node <= NN) rowp[node] = base;
  cur[t] = base;
  __syncthreads();
  for (int i = segs_ex + t; i < sege; i += 256) {
    int p = ebuf[i];
    int pos = atomicAdd(&cur[(p >> 16) & 255], 1);
    col[pos] = p & 0xFFFF;
  }
  if (b == 0 && t == 0) rowp[NN] = ET;
}

// ---------- fused Layer-1 aggregation + GEMM2 MFMA ------------------------
__global__ __launch_bounds__(256) void k_agg1g2(const int* __restrict__ rowp,
    const int* __restrict__ col, const float* __restrict__ a_src,
    const float* __restrict__ a_dst, const u16* __restrict__ h1b,
    const float* __restrict__ b1, const u16* __restrict__ Bbuf2,
    const float* __restrict__ asw2, const float* __restrict__ adw2,
    u16* __restrict__ h2b, float* __restrict__ a_src2, float* __restrict__ a_dst2) {
  __shared__ __align__(16) u16 xtile[16][XT_STRIDE];
  __shared__ float sp_s[4][16];
  __shared__ float sp_d[4][16];
  const int tid = threadIdx.x;
  const int w = tid >> 6, lane = tid & 63;
  const int half = lane >> 5;
  const int hl = lane & 31;
  const int h = hl >> 2;
  const int node0 = blockIdx.x * 16;

  // ---- phase 1: aggregate 4 nodes per wave ----
  for (int nd = 0; nd < 4; nd++) {
    const int node = node0 + w * 4 + nd;
    const float ad = a_dst[node * NH + h];
    float num[8] = {};
    float den = 0.f;
    const int beg = rowp[node], end = rowp[node + 1];
    int e = beg + half;
    int s0 = (e < end) ? col[e] : 0;
    int s1 = (e + 2 < end) ? col[e + 2] : 0;
    while (e + 2 < end) {
      const int cs0 = s0, cs1 = s1;
      if (e + 4 < end) s0 = col[e + 4];
      if (e + 6 < end) s1 = col[e + 6];
      float w0 = __expf(lrelu(a_src[cs0 * NH + h] + ad));
      float w1 = __expf(lrelu(a_src[cs1 * NH + h] + ad));
      uint4 hv0 = ((const uint4*)(h1b + (size_t)cs0 * HID))[hl];
      uint4 hv1 = ((const uint4*)(h1b + (size_t)cs1 * HID))[hl];
      den += w0 + w1;
      num[0] += w0 * bfl(hv0.x) + w1 * bfl(hv1.x);
      num[1] += w0 * bfh(hv0.x) + w1 * bfh(hv1.x);
      num[2] += w0 * bfl(hv0.y) + w1 * bfl(hv1.y);
      num[3] += w0 * bfh(hv0.y) + w1 * bfh(hv1.y);
      num[4] += w0 * bfl(hv0.z) + w1 * bfl(hv1.z);
      num[5] += w0 * bfh(hv0.z) + w1 * bfh(hv1.z);
      num[6] += w0 * bfl(hv0.w) + w1 * bfl(hv1.w);
      num[7] += w0 * bfh(hv0.w) + w1 * bfh(hv1.w);
      e += 4;
    }
    if (e < end) {
      float w0 = __expf(lrelu(a_src[s0 * NH + h] + ad));
      uint4 hv0 = ((const uint4*)(h1b + (size_t)s0 * HID))[hl];
      den += w0;
      num[0] += w0 * bfl(hv0.x); num[1] += w0 * bfh(hv0.x);
      num[2] += w0 * bfl(hv0.y); num[3] += w0 * bfh(hv0.y);
      num[4] += w0 * bfl(hv0.z); num[5] += w0 * bfh(hv0.z);
      num[6] += w0 * bfl(hv0.w); num[7] += w0 * bfh(hv0.w);
    }
    den += __shfl_xor(den, 32, 64);
#pragma unroll
    for (int j = 0; j < 8; j++) num[j] += __shfl_xor(num[j], 32, 64);
    if (half == 0) {
      const float inv = 1.f / (den + 1e-16f);
      const float4 b0 = ((const float4*)(b1 + hl * 8))[0];
      const float4 b1v = ((const float4*)(b1 + hl * 8))[1];
      float o[8];
      o[0] = elu(num[0] * inv + b0.x);
      o[1] = elu(num[1] * inv + b0.y);
      o[2] = elu(num[2] * inv + b0.z);
      o[3] = elu(num[3] * inv + b0.w);
      o[4] = elu(num[4] * inv + b1v.x);
      o[5] = elu(num[5] * inv + b1v.y);
      o[6] = elu(num[6] * inv + b1v.z);
      o[7] = elu(num[7] * inv + b1v.w);
      unsigned int dw[4];
#pragma unroll
      for (int jp = 0; jp < 4; jp++)
        dw[jp] = (unsigned int)f2bf(o[2 * jp]) | ((unsigned int)f2bf(o[2 * jp + 1]) << 16);
      *((uint4*)&xtile[w * 4 + nd][hl * 8]) = (uint4){dw[0], dw[1], dw[2], dw[3]};
    }
  }
  __syncthreads();

  // ---- phase 2: gemm2 for cols [16w, 16w+16) over the 16-node tile ----
  const int quad = lane >> 4, qr = lane & 15;
  f32x4 acc = (f32x4){0.f, 0.f, 0.f, 0.f};
  const bf16x8* Bf = (const bf16x8*)Bbuf2;
#pragma unroll
  for (int kt = 0; kt < 8; kt++) {
    bf16x8 Afrag = *((const bf16x8*)&xtile[qr][kt * 32 + quad * 8]);
    bf16x8 B = Bf[(kt * 4 + w) * 64 + lane];
    acc = __builtin_amdgcn_mfma_f32_16x16x32_bf16(Afrag, B, acc, 0, 0, 0);
  }
  const int colg = w * 16 + qr;
  const float as2 = asw2[colg], ad2 = adw2[colg];
  float vs_p[4], vd_p[4];
#pragma unroll
  for (int reg = 0; reg < 4; reg++) {
    float v = acc[reg];
    int row = quad * 4 + reg;
    h2b[(size_t)(node0 + row) * RP + colg] = f2bf(v);
    vs_p[reg] = v * as2;
    vd_p[reg] = v * ad2;
  }
#pragma unroll
  for (int reg = 0; reg < 4; reg++) {
    float vs = vs_p[reg], vd = vd_p[reg];
    vs += __shfl_xor(vs, 8, 64); vs += __shfl_xor(vs, 4, 64);
    vs += __shfl_xor(vs, 2, 64); vs += __shfl_xor(vs, 1, 64);
    vd += __shfl_xor(vd, 8, 64); vd += __shfl_xor(vd, 4, 64);
    vd += __shfl_xor(vd, 2, 64); vd += __shfl_xor(vd, 1, 64);
    if (qr == 0) {
      sp_s[w][quad * 4 + reg] = vs;
      sp_d[w][quad * 4 + reg] = vd;
    }
  }
  __syncthreads();
  if (tid < 16) {
    a_src2[node0 + tid] = sp_s[0][tid] + sp_s[1][tid] + sp_s[2][tid] + sp_s[3][tid];
    a_dst2[node0 + tid] = sp_d[0][tid] + sp_d[1][tid] + sp_d[2][tid] + sp_d[3][tid];
  }
}

// ---------- Layer-2 aggregation: quarter-wave, 4 edges in flight ----------
__global__ __launch_bounds__(256) void k_agg2(const int* __restrict__ rowp,
    const int* __restrict__ col, const float* __restrict__ a_src2,
    const float* __restrict__ a_dst2, const u16* __restrict__ h2b,
    const float* __restrict__ b2, float* __restrict__ out) {
  int node = (blockIdx.x * 256 + threadIdx.x) >> 6;
  if (node >= NN) return;
  const int lane = threadIdx.x & 63;
  const int q = lane >> 4;
  const int ql = lane & 15;     // owns cols 4*ql .. 4*ql+3
  const float ad = a_dst2[node];
  float num[4] = {};
  float den = 0.f;
  const int beg = rowp[node], end = rowp[node + 1];
  int e = beg + q;
  int s0 = (e < end) ? col[e] : 0;
  int s1 = (e + 4 < end) ? col[e + 4] : 0;
  int s2 = (e + 8 < end) ? col[e + 8] : 0;
  int s3 = (e + 12 < end) ? col[e + 12] : 0;
  while (e + 12 < end) {
    const int cs0 = s0, cs1 = s1, cs2 = s2, cs3 = s3;
    if (e + 16 < end) s0 = col[e + 16];
    if (e + 20 < end) s1 = col[e + 20];
    if (e + 24 < end) s2 = col[e + 24];
    if (e + 28 < end) s3 = col[e + 28];
    float w0 = __expf(lrelu(a_src2[cs0] + ad));
    float w1 = __expf(lrelu(a_src2[cs1] + ad));
    float w2 = __expf(lrelu(a_src2[cs2] + ad));
    float w3 = __expf(lrelu(a_src2[cs3] + ad));
    uint2 hv0 = ((const uint2*)(h2b + (size_t)cs0 * RP))[ql];
    uint2 hv1 = ((const uint2*)(h2b + (size_t)cs1 * RP))[ql];
    uint2 hv2 = ((const uint2*)(h2b + (size_t)cs2 * RP))[ql];
    uint2 hv3 = ((const uint2*)(h2b + (size_t)cs3 * RP))[ql];
    den += (w0 + w1) + (w2 + w3);
    num[0] += w0 * bfl(hv0.x) + w1 * bfl(hv1.x) + w2 * bfl(hv2.x) + w3 * bfl(hv3.x);
    num[1] += w0 * bfh(hv0.x) + w1 * bfh(hv1.x) + w2 * bfh(hv2.x) + w3 * bfh(hv3.x);
    num[2] += w0 * bfl(hv0.y) + w1 * bfl(hv1.y) + w2 * bfl(hv2.y) + w3 * bfl(hv3.y);
    num[3] += w0 * bfh(hv0.y) + w1 * bfh(hv1.y) + w2 * bfh(hv2.y) + w3 * bfh(hv3.y);
    e += 16;
  }
  for (; e < end; e += 4) {
    int s = col[e];
    float w0 = __expf(lrelu(a_src2[s] + ad));
    uint2 hv0 = ((const uint2*)(h2b + (size_t)s * RP))[ql];
    den += w0;
    num[0] += w0 * bfl(hv0.x); num[1] += w0 * bfh(hv0.x);
    num[2] += w0 * bfl(hv0.y); num[3] += w0 * bfh(hv0.y);
  }
  den += __shfl_xor(den, 16, 64);
  den += __shfl_xor(den, 32, 64);
#pragma unroll
  for (int j = 0; j < 4; j++) {
    num[j] += __shfl_xor(num[j], 16, 64);
    num[j] += __shfl_xor(num[j], 32, 64);
  }
  if (q == 0) {
    const float inv = 1.f / (den + 1e-16f);
    const float4 b = ((const float4*)(b2 + ql * 4))[0];
    float4 o;
    o.x = num[0] * inv + b.x;
    o.y = num[1] * inv + b.y;
    o.z = num[2] * inv + b.z;
    o.w = num[3] * inv + b.w;
    ((float4*)(out + (size_t)node * RP + ql * 4))[0] = o;
  }
}

extern "C" void kernel_launch(void* const* d_in, const int* in_sizes, int n_in,
                              void* d_out, int out_size, void* d_ws, size_t ws_size,
                              hipStream_t stream) {
  const float* x   = (const float*)d_in[0];
  const float* W1  = (const float*)d_in[1];
  const float* a1s = (const float*)d_in[2];
  const float* a1d = (const float*)d_in[3];
  const float* b1  = (const float*)d_in[4];
  const float* W2  = (const float*)d_in[5];
  const float* a2s = (const float*)d_in[6];
  const float* a2d = (const float*)d_in[7];
  const float* b2  = (const float*)d_in[8];
  const int*   es  = (const int*)d_in[9];
  const int*   ed  = es + EE;
  float* out = (float*)d_out;

  // workspace layout
  u16*   h1b   = (u16*)d_ws;                        // N*256 bf16
  u16*   h2b   = h1b + (size_t)NN * HID;            // N*64 bf16
  float* asrc1 = (float*)(h2b + (size_t)NN * RP);   // N*8
  float* adst1 = asrc1 + (size_t)NN * NH;           // N*8
  float* asrc2 = adst1 + (size_t)NN * NH;           // N
  float* adst2 = asrc2 + NN;                        // N
  int*   rowp  = (int*)(adst2 + NN);                // N+1
  int*   col   = rowp + NN + 1;                     // ET
  int*   Gh    = col + ET;                          // HBLK*256
  int*   ebuf  = Gh + HBLK * 256;                   // ET packed edges
  int*   btot  = ebuf + ET;                         // 256
  u16*   Bbuf  = (u16*)(btot + 256);                // 128*256 bf16 frag-major
  u16*   Bbuf2 = Bbuf + (size_t)EMB * HID;          // 256*64 bf16 frag-major

  // W prep + chunked edge bucket histograms
  k_pre<<<W1P_BLOCKS + W2P_BLOCKS + HBLK, 256, 0, stream>>>(
      W1, Bbuf, W2, Bbuf2, ed, Gh);

  // MFMA GEMM1 fused with the Gh column-scan
  k_g1<<<G1M_BLOCKS + NBUCK, 256, 0, stream>>>(
      x, Bbuf, a1s, a1d, h1b, asrc1, adst1, Gh, btot);

  k_bscatter<<<HBLK, 256, 0, stream>>>(es, ed, Gh, btot, ebuf);
  k_csr<<<NBUCK, 256, 0, stream>>>(ebuf, btot, rowp, col);

  // fused agg1 + gemm2
  k_agg1g2<<<AGG_BLOCKS, 256, 0, stream>>>(rowp, col, asrc1, adst1, h1b, b1,
                                           Bbuf2, a2s, a2d, h2b, asrc2, adst2);

  k_agg2<<<(NN * 64 + 255) / 256, 256, 0, stream>>>(rowp, col, asrc2, adst2, h2b, b2, out);
}